// Round 1
// baseline (1458.326 us; speedup 1.0000x reference)
//
#include <hip/hip_runtime.h>
#include <math.h>

#define Bc 16
#define Mc 4096
#define Dc 512
#define Nc 8
#define Pc 4
#define Hc 1024
#define NPc 32
#define TOKc (Bc*Mc)

// ws float offsets
#define OFF_PHINT   0u          // [32][512]
#define OFF_INV     16384u      // [65536]
#define OFF_LOGITS  81920u      // [65536][32]
#define OFF_BMAXP   2179072u    // [256]
#define OFF_BMAX    2179328u    // [16]
#define OFF_ZB      2179344u    // [16]
#define OFF_PT      2179360u    // [16][4]
#define OFF_CMAX    2179424u    // [16][32]
#define OFF_CSUMI   2179936u    // [16][32]
#define OFF_SMT     2180448u    // [65536][4]
#define OFF_XS      2442592u    // [512][512]  rows R = b*32+np
#define OFF_XST     2704736u    // [512][512]  transposed [d][R]
#define OFF_HT      2966880u    // [8][1024][64]
#define OFF_L1P     3491168u    // [4][8][64][1024]
#define OFF_L2P     3491168u    // [8][8][64][512] (aliased; l1p consumed first)
#define OFF_YS      5588320u    // [512][512]

__device__ __forceinline__ float block_sum(float v, float* red, int t){
    red[t] = v; __syncthreads();
    for (int o = 128; o > 0; o >>= 1){ if (t < o) red[t] += red[t+o]; __syncthreads(); }
    float r = red[0]; __syncthreads();
    return r;
}
__device__ __forceinline__ float block_max(float v, float* red, int t){
    red[t] = v; __syncthreads();
    for (int o = 128; o > 0; o >>= 1){ if (t < o) red[t] = fmaxf(red[t], red[t+o]); __syncthreads(); }
    float r = red[0]; __syncthreads();
    return r;
}

// K0: phin_t[np][d] = scale * phi[d][np] / max(||phi[:,np]||, 1e-12)
__global__ __launch_bounds__(256) void k_phin(const float* __restrict__ phi,
                                              const float* __restrict__ scale,
                                              float* __restrict__ ws){
    int np = blockIdx.x, t = threadIdx.x;
    __shared__ float red[256];
    float s = 0.f;
    for (int d = t; d < Dc; d += 256){ float v = phi[d*NPc + np]; s += v*v; }
    float ss = block_sum(s, red, t);
    float inv = scale[0] / fmaxf(sqrtf(ss), 1e-12f);
    float* pt = ws + OFF_PHINT + (size_t)np*Dc;
    for (int d = t; d < Dc; d += 256) pt[d] = phi[d*NPc + np] * inv;
}

// K1: logits[tok][np] = (x[tok,:]·phin[:,np]) / ||x[tok,:]||; also inv_norm[tok]
// thread tile: 8 tokens x 4 np, full K=512 per thread
__global__ __launch_bounds__(256) void k_logits(const float* __restrict__ x,
                                                float* __restrict__ ws){
    int t = threadIdx.x;
    int npg = t & 7;          // 8 np-groups of 4
    int tokg = t >> 3;        // 32 token-groups of 8
    int tok0 = blockIdx.x*256 + tokg*8;
    float acc[8][4]; float ssq[8];
#pragma unroll
    for (int i = 0; i < 8; i++){ ssq[i] = 0.f;
#pragma unroll
        for (int j = 0; j < 4; j++) acc[i][j] = 0.f; }
    const float4* xv0 = (const float4*)(x + (size_t)tok0*Dc);
    const float4* pv0 = (const float4*)(ws + OFF_PHINT + (size_t)(npg*4)*Dc);
    for (int k4 = 0; k4 < Dc/4; k4++){
        float4 p[4];
#pragma unroll
        for (int j = 0; j < 4; j++) p[j] = pv0[(size_t)j*(Dc/4) + k4];
#pragma unroll
        for (int i = 0; i < 8; i++){
            float4 xx = xv0[(size_t)i*(Dc/4) + k4];
            ssq[i] += xx.x*xx.x + xx.y*xx.y + xx.z*xx.z + xx.w*xx.w;
#pragma unroll
            for (int j = 0; j < 4; j++)
                acc[i][j] += xx.x*p[j].x + xx.y*p[j].y + xx.z*p[j].z + xx.w*p[j].w;
        }
    }
    float* lg = ws + OFF_LOGITS;
    float* invn = ws + OFF_INV;
#pragma unroll
    for (int i = 0; i < 8; i++){
        float inv = 1.0f / fmaxf(sqrtf(ssq[i]), 1e-12f);
        float4 o; o.x = acc[i][0]*inv; o.y = acc[i][1]*inv; o.z = acc[i][2]*inv; o.w = acc[i][3]*inv;
        *(float4*)(lg + (size_t)(tok0+i)*NPc + npg*4) = o;
        if (npg == 0) invn[tok0+i] = inv;
    }
}

// K2a: per (b,chunk) partial max over 8192 logits
__global__ __launch_bounds__(256) void k_bmax_part(float* __restrict__ ws){
    int t = threadIdx.x;
    __shared__ float red[256];
    const float* lg = ws + OFF_LOGITS + (size_t)blockIdx.x*8192;
    float m = -1e30f;
    for (int i = t; i < 8192; i += 256) m = fmaxf(m, lg[i]);
    float r = block_max(m, red, t);
    if (t == 0) ws[OFF_BMAXP + blockIdx.x] = r;
}
// K2b: final per-batch max
__global__ __launch_bounds__(256) void k_bmax_fin(float* __restrict__ ws){
    int t = threadIdx.x;
    if (t < Bc){
        float m = -1e30f;
        for (int j = 0; j < 16; j++) m = fmaxf(m, ws[OFF_BMAXP + t*16 + j]);
        ws[OFF_BMAX + t] = m;
    }
}

// K2c: S_mt[tok][p] = sum_n exp(l - bmax[b]); Z[b] += sum
__global__ __launch_bounds__(256) void k_smt(float* __restrict__ ws){
    int t = threadIdx.x;
    __shared__ float red[256];
    int tok = blockIdx.x*256 + t;
    int b = tok >> 12;
    float mb = ws[OFF_BMAX + b];
    const float4* lg4 = (const float4*)(ws + OFF_LOGITS + (size_t)tok*NPc);
    float S0=0,S1=0,S2=0,S3=0;
#pragma unroll
    for (int n = 0; n < 8; n++){
        float4 v = lg4[n];
        S0 += expf(v.x - mb); S1 += expf(v.y - mb);
        S2 += expf(v.z - mb); S3 += expf(v.w - mb);
    }
    float4 o; o.x=S0; o.y=S1; o.z=S2; o.w=S3;
    *(float4*)(ws + OFF_SMT + (size_t)tok*4) = o;
    float r = block_sum(S0+S1+S2+S3, red, t);
    if (t == 0) atomicAdd(&ws[OFF_ZB + b], r);
}

// K3: per (b,np) column softmax stats over m (for d)
__global__ __launch_bounds__(256) void k_colstats(float* __restrict__ ws){
    int t = threadIdx.x;
    __shared__ float red[256];
    int b = blockIdx.x >> 5, np = blockIdx.x & 31;
    const float* col = ws + OFF_LOGITS + (size_t)b*Mc*NPc + np;
    float m = -1e30f;
    for (int i = t; i < Mc; i += 256) m = fmaxf(m, col[(size_t)i*NPc]);
    float cm = block_max(m, red, t);
    float s = 0.f;
    for (int i = t; i < Mc; i += 256) s += expf(col[(size_t)i*NPc] - cm);
    float cs = block_sum(s, red, t);
    if (t == 0){ ws[OFF_CMAX + blockIdx.x] = cm; ws[OFF_CSUMI + blockIdx.x] = 1.0f/cs; }
}

// K4a: p_t[b][p]
__global__ __launch_bounds__(256) void k_pt(float* __restrict__ ws){
    int t = threadIdx.x;
    __shared__ float red[256];
    int b = blockIdx.x >> 2, p = blockIdx.x & 3;
    float s = 0.f;
    for (int i = t; i < Mc; i += 256) s += ws[OFF_SMT + ((size_t)(b*Mc + i))*4 + p];
    float r = block_sum(s, red, t);
    if (t == 0) ws[OFF_PT + b*4 + p] = r / ws[OFF_ZB + b];
}

// K4b: mi accumulation
__global__ __launch_bounds__(256) void k_mi(float* __restrict__ ws, float* __restrict__ mi_out){
    int t = threadIdx.x;
    __shared__ float red[256];
    int tok = blockIdx.x*256 + t;
    int b = tok >> 12;
    float4 S = *(const float4*)(ws + OFF_SMT + (size_t)tok*4);
    float Zi = 1.0f / ws[OFF_ZB + b];
    float pmt[4] = {S.x*Zi, S.y*Zi, S.z*Zi, S.w*Zi};
    float pm = pmt[0]+pmt[1]+pmt[2]+pmt[3];
    float acc = 0.f;
#pragma unroll
    for (int p = 0; p < 4; p++){
        float denom = pm * ws[OFF_PT + b*4 + p];
        float ratio = (denom > 0.f) ? pmt[p]/denom : 0.f;
        acc += pmt[p]*logf(ratio + 1e-10f);
    }
    float r = block_sum(acc, red, t);
    if (t == 0) atomicAdd(mi_out, -r);
}

// K_init: xs = task_emb broadcast
__global__ __launch_bounds__(256) void k_xsinit(float* __restrict__ ws, const float* __restrict__ temb){
    int idx = blockIdx.x*256 + threadIdx.x;    // (b*32+np)*512 + d
    int d = idx & 511;
    int np = (idx >> 9) & 31;
    ws[OFF_XS + idx] = temb[(np & 3)*Dc + d];
}

// K5: xs[b][np][:] += sum_m x[tok]*inv_norm * d[tok][np]
__global__ __launch_bounds__(256) void k_xs(const float* __restrict__ x, float* __restrict__ ws){
    int t = threadIdx.x;
    int b = blockIdx.x >> 4, mc = blockIdx.x & 15;
    int npp = t & 15, dg = t >> 4;
    __shared__ float wl[8][32];
    float acc[2][32];
#pragma unroll
    for (int j = 0; j < 2; j++)
#pragma unroll
        for (int q = 0; q < 32; q++) acc[j][q] = 0.f;
    float scm = ws[OFF_CMAX + b*NPc + (t & 31)];
    float sci = ws[OFF_CSUMI + b*NPc + (t & 31)];
    for (int ph = 0; ph < 32; ph++){
        int jt = ph*8 + (t >> 5);
        int tok = b*Mc + mc*256 + jt;
        float l = ws[OFF_LOGITS + (size_t)tok*NPc + (t & 31)];
        float w = expf(l - scm) * sci * ws[OFF_INV + tok];
        __syncthreads();
        wl[t >> 5][t & 31] = w;
        __syncthreads();
        for (int j = 0; j < 8; j++){
            int tokj = b*Mc + mc*256 + ph*8 + j;
            const float4* xr = (const float4*)(x + (size_t)tokj*Dc + dg*32);
            float w0 = wl[j][npp*2], w1 = wl[j][npp*2+1];
#pragma unroll
            for (int q = 0; q < 8; q++){
                float4 xx = xr[q];
                acc[0][q*4+0] += w0*xx.x; acc[0][q*4+1] += w0*xx.y;
                acc[0][q*4+2] += w0*xx.z; acc[0][q*4+3] += w0*xx.w;
                acc[1][q*4+0] += w1*xx.x; acc[1][q*4+1] += w1*xx.y;
                acc[1][q*4+2] += w1*xx.z; acc[1][q*4+3] += w1*xx.w;
            }
        }
    }
#pragma unroll
    for (int jj = 0; jj < 2; jj++){
        int np = npp*2 + jj;
        float* dst = ws + OFF_XS + ((size_t)(b*NPc + np))*Dc + dg*32;
#pragma unroll
        for (int q = 0; q < 32; q++) atomicAdd(dst + q, acc[jj][q]);
    }
}

// K5t: transpose xs -> xsT[d][R]
__global__ __launch_bounds__(256) void k_xst(float* __restrict__ ws){
    int t = threadIdx.x;
    __shared__ float ld[64][65];
    int Rt = blockIdx.x >> 3, Dt = blockIdx.x & 7;
    int r0 = Rt*64, d0 = Dt*64;
    for (int i = 0; i < 16; i++){
        int rl = i*4 + (t >> 6), dl = t & 63;
        ld[rl][dl] = ws[OFF_XS + (size_t)(r0+rl)*Dc + d0 + dl];
    }
    __syncthreads();
    for (int i = 0; i < 16; i++){
        int dl = i*4 + (t >> 6), rl = t & 63;
        ws[OFF_XST + (size_t)(d0+dl)*512 + r0 + rl] = ld[rl][dl];
    }
}

// K6a: layer1 partials: l1p[ks][n][rl][h] = sum_{k in ks} xsT[k][R]·W1[n][k][h]
__global__ __launch_bounds__(256) void k_l1(float* __restrict__ ws, const float* __restrict__ W1){
    int t = threadIdx.x;
    int n = blockIdx.x, hc = blockIdx.y, ks = blockIdx.z;
    int h0 = hc*128, k0 = ks*128;
    int hg = t & 15, rg = t >> 4;    // rg = b
    float acc[4][8];
#pragma unroll
    for (int p = 0; p < 4; p++)
#pragma unroll
        for (int j = 0; j < 8; j++) acc[p][j] = 0.f;
    const float* xst = ws + OFF_XST;
    const float* w1p = W1 + (size_t)n*Dc*Hc;
    for (int k = k0; k < k0+128; k++){
        float4 xv = *(const float4*)(xst + (size_t)k*512 + rg*32 + n*4);
        float4 wa = *(const float4*)(w1p + (size_t)k*Hc + h0 + hg*8);
        float4 wb = *(const float4*)(w1p + (size_t)k*Hc + h0 + hg*8 + 4);
        float wv[8] = {wa.x, wa.y, wa.z, wa.w, wb.x, wb.y, wb.z, wb.w};
#pragma unroll
        for (int j = 0; j < 8; j++){
            acc[0][j] += xv.x*wv[j]; acc[1][j] += xv.y*wv[j];
            acc[2][j] += xv.z*wv[j]; acc[3][j] += xv.w*wv[j];
        }
    }
    float* outp = ws + OFF_L1P + (size_t)(ks*8 + n)*64*Hc;
#pragma unroll
    for (int p = 0; p < 4; p++){
        int rl = rg*4 + p;
        float4 oa, ob;
        oa.x = acc[p][0]; oa.y = acc[p][1]; oa.z = acc[p][2]; oa.w = acc[p][3];
        ob.x = acc[p][4]; ob.y = acc[p][5]; ob.z = acc[p][6]; ob.w = acc[p][7];
        *(float4*)(outp + (size_t)rl*Hc + h0 + hg*8) = oa;
        *(float4*)(outp + (size_t)rl*Hc + h0 + hg*8 + 4) = ob;
    }
}

// K6a2: combine ksplit + bias + silu -> hT[n][h][rl]
__global__ __launch_bounds__(256) void k_l1c(float* __restrict__ ws, const float* __restrict__ b1){
    int t = threadIdx.x;
    __shared__ float ld[64][65];
    int n = blockIdx.x, h0 = blockIdx.y*64;
    for (int i = 0; i < 16; i++){
        int rl = i*4 + (t >> 6), hl = t & 63;
        float s = b1[n*Hc + h0 + hl];
        for (int ks = 0; ks < 4; ks++)
            s += ws[OFF_L1P + (size_t)(ks*8 + n)*64*Hc + (size_t)rl*Hc + h0 + hl];
        s = s / (1.0f + expf(-s));
        ld[rl][hl] = s;
    }
    __syncthreads();
    for (int i = 0; i < 16; i++){
        int hl = i*4 + (t >> 6), rl = t & 63;
        ws[OFF_HT + ((size_t)n*Hc + h0 + hl)*64 + rl] = ld[rl][hl];
    }
}

// K6b: layer2 partials: l2p[ks][n][rl][d]
__global__ __launch_bounds__(256) void k_l2(float* __restrict__ ws, const float* __restrict__ W2){
    int t = threadIdx.x;
    int n = blockIdx.x, dc = blockIdx.y, ks = blockIdx.z;
    int d0 = dc*128, k0 = ks*128;
    int dgl = t & 15, rg = t >> 4;
    float acc[4][8];
#pragma unroll
    for (int p = 0; p < 4; p++)
#pragma unroll
        for (int j = 0; j < 8; j++) acc[p][j] = 0.f;
    const float* w2p = W2 + (size_t)n*Hc*Dc;
    const float* htp = ws + OFF_HT + (size_t)n*Hc*64;
    for (int k = k0; k < k0+128; k++){
        float4 hv = *(const float4*)(htp + (size_t)k*64 + rg*4);
        float4 wa = *(const float4*)(w2p + (size_t)k*Dc + d0 + dgl*8);
        float4 wb = *(const float4*)(w2p + (size_t)k*Dc + d0 + dgl*8 + 4);
        float wv[8] = {wa.x, wa.y, wa.z, wa.w, wb.x, wb.y, wb.z, wb.w};
#pragma unroll
        for (int j = 0; j < 8; j++){
            acc[0][j] += hv.x*wv[j]; acc[1][j] += hv.y*wv[j];
            acc[2][j] += hv.z*wv[j]; acc[3][j] += hv.w*wv[j];
        }
    }
    float* outp = ws + OFF_L2P + (size_t)(ks*8 + n)*64*Dc;
#pragma unroll
    for (int p = 0; p < 4; p++){
        int rl = rg*4 + p;
        float4 oa, ob;
        oa.x = acc[p][0]; oa.y = acc[p][1]; oa.z = acc[p][2]; oa.w = acc[p][3];
        ob.x = acc[p][4]; ob.y = acc[p][5]; ob.z = acc[p][6]; ob.w = acc[p][7];
        *(float4*)(outp + (size_t)rl*Dc + d0 + dgl*8) = oa;
        *(float4*)(outp + (size_t)rl*Dc + d0 + dgl*8 + 4) = ob;
    }
}

// K6c: combine + bias + residual + LayerNorm -> ys[R][d]
__global__ __launch_bounds__(256) void k_lnc(float* __restrict__ ws, const float* __restrict__ b2,
                                             const float* __restrict__ lng, const float* __restrict__ lnb){
    int t = threadIdx.x;
    __shared__ float red[256];
    int n = blockIdx.x >> 6, rl = blockIdx.x & 63;
    int Rg = (rl >> 2)*32 + n*4 + (rl & 3);
    float v[2];
#pragma unroll
    for (int h = 0; h < 2; h++){
        int d = t + h*256;
        float s = b2[n*Dc + d] + ws[OFF_XS + (size_t)Rg*Dc + d];
        for (int ks = 0; ks < 8; ks++)
            s += ws[OFF_L2P + (size_t)(ks*8 + n)*64*Dc + (size_t)rl*Dc + d];
        v[h] = s;
    }
    float mu = block_sum(v[0] + v[1], red, t) * (1.0f/512.0f);
    float d0 = v[0]-mu, d1 = v[1]-mu;
    float var = block_sum(d0*d0 + d1*d1, red, t) * (1.0f/512.0f);
    float rs = 1.0f / sqrtf(var + 1e-5f);
#pragma unroll
    for (int h = 0; h < 2; h++){
        int d = t + h*256;
        ws[OFF_YS + (size_t)Rg*Dc + d] = (v[h]-mu)*rs*lng[n*Dc + d] + lnb[n*Dc + d];
    }
}

// K7: c = softmax over (n,p); y[b][m][p][:] = sum_n ys[b][n*4+p][:]*c[n][p]
__global__ __launch_bounds__(256) void k_y(const float* __restrict__ ws,
                                           float* __restrict__ c_out, float* __restrict__ y_out){
    int t = threadIdx.x;
    int b = blockIdx.x >> 7, mc = blockIdx.x & 127;
    int p = t >> 6, d0 = (t & 63)*8;
    __shared__ float cl[32][32];
    for (int ph = 0; ph < 4; ph++){
        int jt = ph*8 + (t >> 5);
        int tok = b*Mc + mc*32 + jt;
        float l = ws[OFF_LOGITS + (size_t)tok*NPc + (t & 31)];
        float mx = l;
        for (int s = 16; s; s >>= 1) mx = fmaxf(mx, __shfl_xor(mx, s, 32));
        float e = expf(l - mx);
        float sm = e;
        for (int s = 16; s; s >>= 1) sm += __shfl_xor(sm, s, 32);
        float c = e/sm;
        cl[jt][t & 31] = c;
        c_out[(size_t)tok*NPc + (t & 31)] = c;
    }
    float4 ya[8], yb[8];
#pragma unroll
    for (int n = 0; n < 8; n++){
        const float* base = ws + OFF_YS + (size_t)(b*NPc + n*4 + p)*Dc + d0;
        ya[n] = ((const float4*)base)[0];
        yb[n] = ((const float4*)base)[1];
    }
    __syncthreads();
    for (int j = 0; j < 32; j++){
        float4 u = {0,0,0,0}, v = {0,0,0,0};
#pragma unroll
        for (int n = 0; n < 8; n++){
            float c = cl[j][n*4 + p];
            u.x += ya[n].x*c; u.y += ya[n].y*c; u.z += ya[n].z*c; u.w += ya[n].w*c;
            v.x += yb[n].x*c; v.y += yb[n].y*c; v.z += yb[n].z*c; v.w += yb[n].w*c;
        }
        float* yo = y_out + ((size_t)(b*Mc + mc*32 + j)*Pc + p)*Dc + d0;
        ((float4*)yo)[0] = u;
        ((float4*)yo)[1] = v;
    }
}

extern "C" void kernel_launch(void* const* d_in, const int* in_sizes, int n_in,
                              void* d_out, int out_size, void* d_ws, size_t ws_size,
                              hipStream_t stream) {
    const float* x    = (const float*)d_in[0];
    const float* phi  = (const float*)d_in[1];
    const float* scal = (const float*)d_in[2];
    const float* temb = (const float*)d_in[3];
    const float* W1   = (const float*)d_in[4];
    const float* b1   = (const float*)d_in[5];
    const float* W2   = (const float*)d_in[6];
    const float* b2   = (const float*)d_in[7];
    const float* lng  = (const float*)d_in[8];
    const float* lnb  = (const float*)d_in[9];
    float* out = (float*)d_out;
    float* y_out = out;
    float* c_out = out + (size_t)Bc*Mc*Pc*Dc;
    float* mi_out = c_out + (size_t)Bc*Mc*Nc*Pc;
    float* ws = (float*)d_ws;

    hipMemsetAsync(ws + OFF_ZB, 0, 16*sizeof(float), stream);
    hipMemsetAsync(mi_out, 0, sizeof(float), stream);

    k_phin     <<<32,   256, 0, stream>>>(phi, scal, ws);
    k_logits   <<<256,  256, 0, stream>>>(x, ws);
    k_bmax_part<<<256,  256, 0, stream>>>(ws);
    k_bmax_fin <<<1,    256, 0, stream>>>(ws);
    k_smt      <<<256,  256, 0, stream>>>(ws);
    k_colstats <<<512,  256, 0, stream>>>(ws);
    k_pt       <<<64,   256, 0, stream>>>(ws);
    k_mi       <<<256,  256, 0, stream>>>(ws, mi_out);
    k_xsinit   <<<1024, 256, 0, stream>>>(ws, temb);
    k_xs       <<<256,  256, 0, stream>>>(x, ws);
    k_xst      <<<64,   256, 0, stream>>>(ws);
    k_l1       <<<dim3(8,8,4),  256, 0, stream>>>(ws, W1);
    k_l1c      <<<dim3(8,16),   256, 0, stream>>>(ws, b1);
    k_l2       <<<dim3(8,4,8),  256, 0, stream>>>(ws, W2);
    k_lnc      <<<512,  256, 0, stream>>>(ws, b2, lng, lnb);
    k_y        <<<2048, 256, 0, stream>>>(ws, c_out, y_out);
}